// Round 6
// baseline (900.012 us; speedup 1.0000x reference)
//
#include <hip/hip_runtime.h>

typedef short short8 __attribute__((ext_vector_type(8)));
typedef float f32x4 __attribute__((ext_vector_type(4)));
typedef unsigned short u16;
typedef unsigned int u32;

__device__ __forceinline__ u32 cvt2(float a, float b) {
    u32 r; asm("v_cvt_pk_bf16_f32 %0, %1, %2" : "=v"(r) : "v"(a), "v"(b)); return r;
}
__device__ __forceinline__ u16 f2bf(float f) {
    u32 r; asm("v_cvt_pk_bf16_f32 %0, %1, %1" : "=v"(r) : "v"(f)); return (u16)r;
}
__device__ __forceinline__ float bf2f(u16 b) {
    union { u32 u; float f; } v; v.u = ((u32)b) << 16; return v.f;
}
// async global->LDS DMA, 16B per lane, dest = wave-uniform base + lane*16
__device__ __forceinline__ void gload_lds16(const u16* g, u16* l) {
    __builtin_amdgcn_global_load_lds((const __attribute__((address_space(1))) void*)g,
                                     (__attribute__((address_space(3))) void*)l, 16, 0, 0);
}

// Stage K-slice u (32 cols) of Wt[N][K] rows [0,TILE_N) into Bbuf slot (u&1).
// 16B-chunk XOR swizzle: LDS slot s of row r holds global chunk s ^ ((r>>1)&3)
// (linear DMA dest + inverse-swizzled source; reads apply the same XOR).
template<int K, int TILE_N, int NW>
__device__ __forceinline__ void stageB(const u16* __restrict__ Wt, u16* Bbuf, int u) {
    constexpr int R16 = TILE_N / 16;
    const int wave = threadIdx.x >> 6;
    const int lane = threadIdx.x & 63;
    const u16* wsrc = Wt + u * 32;
    u16* dst0 = Bbuf + (u & 1) * (TILE_N * 32);
    for (int rg = wave; rg < R16; rg += NW) {
        int n_local = rg * 16 + (lane >> 2);
        int chunk = (lane & 3) ^ ((n_local >> 1) & 3);
        gload_lds16(wsrc + (size_t)n_local * K + chunk * 8, dst0 + rg * 512);
    }
}

// One MLP layer: X (bf16 LDS [MG*64][K+8]) @ Wt (bf16 global [N][K]) + bias,
// row LayerNorm, opt SiLU.  NW waves as MG row-groups x NWC col-waves; every wave active.
// B (full N x 32 K-slice) double-buffered in LDS via async DMA; one __syncthreads per
// K-slice (its implicit vmcnt/lgkm drain is the pipeline wait).  Caller issues stage(0).
// Cross-wave LN reduce via LDS float atomics into red_cur[(row)*2+{0,1}]; red_next zeroed.
// OMODE 0: bf16 to Ol (stride N+8).  OMODE 1: fused global epilogue (residual+mask+bout).
template<int K, int N, int NW, int MG, bool SILU, int OMODE, typename F>
__device__ __forceinline__ void mlp_layer(
    const u16* Xl, u16* Ol, u16* Bbuf,
    float* red_cur, float* red_next,
    const u16* __restrict__ Wt, const float* __restrict__ bias,
    const float* __restrict__ gamma, const float* __restrict__ beta,
    F&& prestage,
    const float* resid, float* gout, u16* bout, const u32* degv, int rowsv)
{
    constexpr int LDX = K + 8;
    constexpr int LDO = N + 8;
    constexpr int NWC = NW / MG;
    constexpr int NT = N / (16 * NWC);
    constexpr int U = K / 32;
    constexpr int WS = N / NWC;
    constexpr int ROWS = MG * 64;
    static_assert(N % (16 * NWC) == 0 && NT >= 1, "bad split");
    const int tid = threadIdx.x;
    const int wave = tid >> 6;
    const int lane = tid & 63;
    const int l15 = lane & 15;
    const int lg = lane >> 4;
    const int mgrp = wave / NWC;
    const int cwave = wave % NWC;
    const int xrow0 = mgrp * 64;

    // preload LN params; latency hides under the K-loop
    float bv[NT], gv[NT], btv[NT];
    #pragma unroll
    for (int j = 0; j < NT; ++j) {
        int col = cwave * WS + j * 16 + l15;
        bv[j] = bias[col]; gv[j] = gamma[col]; btv[j] = beta[col];
    }

    f32x4 acc[4][NT];
    #pragma unroll
    for (int mt = 0; mt < 4; ++mt)
        #pragma unroll
        for (int j = 0; j < NT; ++j)
            acc[mt][j] = (f32x4){0.f, 0.f, 0.f, 0.f};

    short8 a[4];
    for (int u = 0; u < U; ++u) {
        __syncthreads();                       // stage(u) DMA + prior LDS writes visible
        if (u + 1 < U) stageB<K, N, NW>(Wt, Bbuf, u + 1);
        const u16* bb = Bbuf + (u & 1) * (N * 32);
        #pragma unroll
        for (int mt = 0; mt < 4; ++mt)
            a[mt] = *(const short8*)(Xl + (xrow0 + mt * 16 + l15) * LDX + u * 32 + lg * 8);
        #pragma unroll
        for (int nt = 0; nt < NT; ++nt) {
            int r = cwave * WS + nt * 16 + l15;
            short8 b = *(const short8*)(bb + r * 32 + ((lg ^ ((r >> 1) & 3)) << 3));
            #pragma unroll
            for (int mt = 0; mt < 4; ++mt)
                acc[mt][nt] = __builtin_amdgcn_mfma_f32_16x16x32_bf16(a[mt], b, acc[mt][nt], 0, 0, 0);
        }
    }
    prestage();   // next layer's stage(0); slot 0 is free (U even), hides under LN

    // bias + per-row (sum, sumsq) partials; C/D layout: col=l15, row=lg*4+r
    #pragma unroll
    for (int mt = 0; mt < 4; ++mt) {
        float s[4] = {0.f, 0.f, 0.f, 0.f}, q[4] = {0.f, 0.f, 0.f, 0.f};
        #pragma unroll
        for (int j = 0; j < NT; ++j)
            #pragma unroll
            for (int r = 0; r < 4; ++r) {
                float v = acc[mt][j][r] + bv[j];
                acc[mt][j][r] = v;
                s[r] += v; q[r] += v * v;
            }
        #pragma unroll
        for (int o = 1; o < 16; o <<= 1)
            #pragma unroll
            for (int r = 0; r < 4; ++r) {
                s[r] += __shfl_xor(s[r], o, 64);
                q[r] += __shfl_xor(q[r], o, 64);
            }
        if (l15 == 0) {
            int row = xrow0 + mt * 16 + lg * 4;
            #pragma unroll
            for (int r = 0; r < 4; ++r) {
                atomicAdd(&red_cur[(row + r) * 2 + 0], s[r]);
                atomicAdd(&red_cur[(row + r) * 2 + 1], q[r]);
            }
        }
    }
    __syncthreads();                          // B1: partials complete; all X reads done
    if (tid < ROWS * 2) red_next[tid] = 0.f;  // ping-pong buffer for next layer
    {
        constexpr float invN = 1.f / (float)N;
        #pragma unroll
        for (int mt = 0; mt < 4; ++mt)
            #pragma unroll
            for (int r = 0; r < 4; ++r) {
                int row = xrow0 + mt * 16 + lg * 4 + r;
                float2 sq = *(const float2*)&red_cur[row * 2];
                float mean = sq.x * invN;
                float rstd = rsqrtf(sq.y * invN - mean * mean + 1e-5f);
                #pragma unroll
                for (int j = 0; j < NT; ++j) {
                    float h = (acc[mt][j][r] - mean) * rstd * gv[j] + btv[j];
                    if (SILU) h = h * __builtin_amdgcn_rcpf(1.f + __expf(-h));
                    int col = cwave * WS + j * 16 + l15;
                    if (OMODE == 0) {
                        Ol[row * LDO + col] = f2bf(h);
                    } else if (row < rowsv) {
                        float base = resid[row * 128 + col];
                        float val = h;
                        if (degv) val = (degv[row] > 0u) ? h : 0.f;
                        gout[row * 128 + col] = base + val;
                        if (bout) bout[row * 128 + col] = f2bf(h);
                    }
                }
            }
    }
    if (OMODE == 0) __syncthreads();          // B2: Ol visible (Ol may alias Xl)
}

// ---------------- edge binning: elist[dst*64 + slot] = e
__global__ __launch_bounds__(256) void bin_kernel(
    const int* __restrict__ dst_idx, u32* __restrict__ cursor,
    int* __restrict__ elist, int E)
{
    int e = blockIdx.x * 256 + threadIdx.x;
    if (e < E) {
        int d = dst_idx[e];
        u32 slot = atomicAdd(&cursor[d], 1u);
        if (slot < 64u) elist[(size_t)d * 64 + slot] = e;
    }
}

// ---------------- edge kernel: 16 waves, 128 edges/block; MLP(384->384->128), fused epilogue
__global__ __launch_bounds__(1024, 4) void edge_kernel(
    const float* __restrict__ e_h, const float* __restrict__ h_src, const float* __restrict__ h_dst,
    const int* __restrict__ src_idx, const int* __restrict__ dst_idx,
    const u16* __restrict__ ew0t, const float* __restrict__ eb0, const float* __restrict__ eg0, const float* __restrict__ ebt0,
    const u16* __restrict__ ew1t, const float* __restrict__ eb1, const float* __restrict__ eg1, const float* __restrict__ ebt1,
    u16* __restrict__ e_new,          // may be null -> dst kernel recomputes from e_out - e_h
    float* __restrict__ e_out, int E)
{
    __shared__ alignas(16) u16 Xbuf[128 * 392];       // 100352 B: X / H1 in place
    __shared__ alignas(16) u16 Bbuf[2 * 384 * 32];    // 49152 B: B double buffer
    __shared__ alignas(8) float red[2][256];          // 2048 B
    const int tid = threadIdx.x;
    const int eBase = blockIdx.x * 128;
    const int rowsv = min(128, E - eBase);

    if (tid < 256) red[0][tid] = 0.f;
    stageB<384, 384, 16>(ew0t, Bbuf, 0);              // stage(0) flies under X gather

    // stage X = [e_h | h_src[s] | h_dst[d]] as bf16; 8 threads/row, 12 float4 each
    {
        const int row = tid >> 3, q8 = tid & 7;
        u16* xr = Xbuf + row * 392;
        if (row < rowsv) {
            int e = eBase + row;
            const float* pe = e_h   + (size_t)e * 128;
            const float* ps = h_src + (size_t)src_idx[e] * 128;
            const float* pd = h_dst + (size_t)dst_idx[e] * 128;
            #pragma unroll
            for (int j = 0; j < 12; ++j) {
                int col = (q8 + j * 8) * 4;            // 0..380
                const float* p = (col < 128) ? (pe + col)
                               : (col < 256) ? (ps + col - 128)
                                             : (pd + col - 256);
                float4 v = *(const float4*)p;
                *(uint2*)(xr + col) = make_uint2(cvt2(v.x, v.y), cvt2(v.z, v.w));
            }
        } else {
            #pragma unroll
            for (int j = 0; j < 12; ++j) {
                int col = (q8 + j * 8) * 4;
                *(uint2*)(xr + col) = make_uint2(0u, 0u);
            }
        }
    }
    // mlp's first __syncthreads covers X writes + B stage(0)

    mlp_layer<384, 384, 16, 2, true, 0>(
        Xbuf, Xbuf, Bbuf, red[0], red[1], ew0t, eb0, eg0, ebt0,
        [&] { stageB<384, 128, 16>(ew1t, Bbuf, 0); },
        nullptr, nullptr, nullptr, nullptr, rowsv);

    mlp_layer<384, 128, 16, 2, false, 1>(
        Xbuf, nullptr, Bbuf, red[1], red[0], ew1t, eb1, eg1, ebt1,
        [&] {},
        e_h + (size_t)eBase * 128, e_out + (size_t)eBase * 128,
        e_new ? e_new + (size_t)eBase * 128 : (u16*)nullptr, nullptr, rowsv);
}

// ---------------- dst kernel: [h_dst | gather-sum(e_new)] -> MLP(256->256->128), deg mask, residual
__global__ __launch_bounds__(512, 4) void dst_kernel(
    const float* __restrict__ h_dst,
    const u16* __restrict__ e_new,       // fast path; may be null
    const float* __restrict__ e_out, const float* __restrict__ e_h,   // fallback
    const int* __restrict__ elist, const u32* __restrict__ cursor,
    const u16* __restrict__ dw0t, const float* __restrict__ db0, const float* __restrict__ dg0, const float* __restrict__ dbt0,
    const u16* __restrict__ dw1t, const float* __restrict__ db1, const float* __restrict__ dg1, const float* __restrict__ dbt1,
    float* __restrict__ hd_out, int ND)
{
    __shared__ alignas(16) u16 Xbuf[64 * 264];        // 33792 B
    __shared__ alignas(16) u16 Bbuf[2 * 256 * 32];    // 32768 B
    __shared__ alignas(8) float red[2][128];
    const int tid = threadIdx.x;
    const int nBase = blockIdx.x * 64;
    const int rowsv = min(64, ND - nBase);

    if (tid < 128) red[0][tid] = 0.f;
    stageB<256, 256, 8>(dw0t, Bbuf, 0);               // hides under gather phase

    // left half: h_dst -> bf16 (8 threads/row, 4 float4 each)
    {
        const int row = tid >> 3, q8 = tid & 7;
        int n = nBase + row;
        u16* xr = Xbuf + row * 264;
        #pragma unroll
        for (int j = 0; j < 4; ++j) {
            int col = (q8 + j * 8) * 4;
            float4 v = make_float4(0.f, 0.f, 0.f, 0.f);
            if (n < ND) v = *(const float4*)(h_dst + (size_t)n * 128 + col);
            *(uint2*)(xr + col) = make_uint2(cvt2(v.x, v.y), cvt2(v.z, v.w));
        }
    }
    // right half: m_sum via per-dst edge-list gather. 8 threads/row, 16 cols each.
    {
        const int r = tid >> 3, q = tid & 7;
        const int n = nBase + r;
        float accm[16];
        #pragma unroll
        for (int c = 0; c < 16; ++c) accm[c] = 0.f;
        if (n < ND) {
            int dg = min((int)cursor[n], 64);
            const int* el = elist + (size_t)n * 64;
            if (e_new) {
                for (int j = 0; j < dg; ++j) {
                    const u16* p = e_new + (size_t)el[j] * 128 + q * 16;
                    #pragma unroll
                    for (int t = 0; t < 2; ++t) {
                        short8 v = *(const short8*)(p + t * 8);
                        #pragma unroll
                        for (int c = 0; c < 8; ++c) accm[t * 8 + c] += bf2f((u16)v[c]);
                    }
                }
            } else {
                for (int j = 0; j < dg; ++j) {
                    const float* po = e_out + (size_t)el[j] * 128 + q * 16;
                    const float* ph = e_h  + (size_t)el[j] * 128 + q * 16;
                    #pragma unroll
                    for (int t = 0; t < 4; ++t) {
                        float4 vo = *(const float4*)(po + t * 4);
                        float4 vh = *(const float4*)(ph + t * 4);
                        accm[t * 4 + 0] += vo.x - vh.x;
                        accm[t * 4 + 1] += vo.y - vh.y;
                        accm[t * 4 + 2] += vo.z - vh.z;
                        accm[t * 4 + 3] += vo.w - vh.w;
                    }
                }
            }
        }
        #pragma unroll
        for (int c4 = 0; c4 < 4; ++c4)
            *(uint2*)(Xbuf + r * 264 + 128 + q * 16 + c4 * 4) =
                make_uint2(cvt2(accm[c4 * 4 + 0], accm[c4 * 4 + 1]),
                           cvt2(accm[c4 * 4 + 2], accm[c4 * 4 + 3]));
    }

    mlp_layer<256, 256, 8, 1, true, 0>(
        Xbuf, Xbuf, Bbuf, red[0], red[1], dw0t, db0, dg0, dbt0,
        [&] { stageB<256, 128, 8>(dw1t, Bbuf, 0); },
        nullptr, nullptr, nullptr, nullptr, rowsv);

    mlp_layer<256, 128, 8, 1, false, 1>(
        Xbuf, nullptr, Bbuf, red[1], red[0], dw1t, db1, dg1, dbt1,
        [&] {},
        h_dst + (size_t)nBase * 128, hd_out + (size_t)nBase * 128,
        (u16*)nullptr, cursor + nBase, rowsv);
}

// ---------------- src kernel: h_src -> MLP(128->128->128), residual
__global__ __launch_bounds__(512, 6) void src_kernel(
    const float* __restrict__ h_src,
    const u16* __restrict__ sw0t, const float* __restrict__ sb0, const float* __restrict__ sg0, const float* __restrict__ sbt0,
    const u16* __restrict__ sw1t, const float* __restrict__ sb1, const float* __restrict__ sg1, const float* __restrict__ sbt1,
    float* __restrict__ hs_out, int NS)
{
    __shared__ alignas(16) u16 Xbuf[64 * 136];
    __shared__ alignas(16) u16 Bbuf[2 * 128 * 32];
    __shared__ alignas(8) float red[2][128];
    const int tid = threadIdx.x;
    const int nBase = blockIdx.x * 64;
    const int rowsv = min(64, NS - nBase);

    if (tid < 128) red[0][tid] = 0.f;
    stageB<128, 128, 8>(sw0t, Bbuf, 0);

    {
        const int row = tid >> 3, q8 = tid & 7;
        int n = nBase + row;
        u16* xr = Xbuf + row * 136;
        #pragma unroll
        for (int j = 0; j < 4; ++j) {
            int col = (q8 + j * 8) * 4;
            float4 v = make_float4(0.f, 0.f, 0.f, 0.f);
            if (n < NS) v = *(const float4*)(h_src + (size_t)n * 128 + col);
            *(uint2*)(xr + col) = make_uint2(cvt2(v.x, v.y), cvt2(v.z, v.w));
        }
    }

    mlp_layer<128, 128, 8, 1, true, 0>(
        Xbuf, Xbuf, Bbuf, red[0], red[1], sw0t, sb0, sg0, sbt0,
        [&] { stageB<128, 128, 8>(sw1t, Bbuf, 0); },
        nullptr, nullptr, nullptr, nullptr, rowsv);

    mlp_layer<128, 128, 8, 1, false, 1>(
        Xbuf, nullptr, Bbuf, red[1], red[0], sw1t, sb1, sg1, sbt1,
        [&] {},
        h_src + (size_t)nBase * 128, hs_out + (size_t)nBase * 128,
        (u16*)nullptr, nullptr, rowsv);
}

// ---------------- weight transpose+cast: W[k][n] f32 -> Wt[n][k] bf16
__global__ __launch_bounds__(256) void wtrans(const float* __restrict__ W, u16* __restrict__ Wt, int K, int N) {
    int i = blockIdx.x * 256 + threadIdx.x;
    if (i < K * N) {
        int k = i / N, n = i % N;
        Wt[(size_t)n * K + k] = f2bf(W[i]);
    }
}

extern "C" void kernel_launch(void* const* d_in, const int* in_sizes, int n_in,
                              void* d_out, int out_size, void* d_ws, size_t ws_size,
                              hipStream_t stream) {
    const float* e_h   = (const float*)d_in[0];
    const float* h_src = (const float*)d_in[1];
    const float* h_dst = (const float*)d_in[2];
    const int* src_idx = (const int*)d_in[3];
    const int* dst_idx = (const int*)d_in[4];
    const float* ew0 = (const float*)d_in[5];
    const float* eb0 = (const float*)d_in[6];
    const float* eg0 = (const float*)d_in[7];
    const float* ebt0 = (const float*)d_in[8];
    const float* ew1 = (const float*)d_in[9];
    const float* eb1 = (const float*)d_in[10];
    const float* eg1 = (const float*)d_in[11];
    const float* ebt1 = (const float*)d_in[12];
    const float* dw0 = (const float*)d_in[13];
    const float* db0 = (const float*)d_in[14];
    const float* dg0 = (const float*)d_in[15];
    const float* dbt0 = (const float*)d_in[16];
    const float* dw1 = (const float*)d_in[17];
    const float* db1 = (const float*)d_in[18];
    const float* dg1 = (const float*)d_in[19];
    const float* dbt1 = (const float*)d_in[20];
    const float* sw0 = (const float*)d_in[21];
    const float* sb0 = (const float*)d_in[22];
    const float* sg0 = (const float*)d_in[23];
    const float* sbt0 = (const float*)d_in[24];
    const float* sw1 = (const float*)d_in[25];
    const float* sb1 = (const float*)d_in[26];
    const float* sg1 = (const float*)d_in[27];
    const float* sbt1 = (const float*)d_in[28];

    const int E  = in_sizes[0] / 128;
    const int NS = in_sizes[1] / 128;
    const int ND = in_sizes[2] / 128;

    // workspace carve-up (16B-aligned chunks)
    char* ws = (char*)d_ws;
    size_t off = 0;
    int* elist = (int*)(ws + off);  off += (size_t)ND * 64 * 4;
    u32* cursor = (u32*)(ws + off); off += (size_t)ND * 4;
    u16* ew0t = (u16*)(ws + off);   off += (size_t)384 * 384 * 2;
    u16* ew1t = (u16*)(ws + off);   off += (size_t)128 * 384 * 2;
    u16* dw0t = (u16*)(ws + off);   off += (size_t)256 * 256 * 2;
    u16* dw1t = (u16*)(ws + off);   off += (size_t)128 * 256 * 2;
    u16* sw0t = (u16*)(ws + off);   off += (size_t)128 * 128 * 2;
    u16* sw1t = (u16*)(ws + off);   off += (size_t)128 * 128 * 2;
    off = (off + 255) & ~(size_t)255;
    u16* e_new = (u16*)(ws + off);
    size_t need = off + (size_t)E * 128 * 2;
    if (ws_size < need) e_new = nullptr;   // fallback: dst kernel recomputes from e_out - e_h

    hipMemsetAsync(cursor, 0, (size_t)ND * 4, stream);

    wtrans<<<(384 * 384 + 255) / 256, 256, 0, stream>>>(ew0, ew0t, 384, 384);
    wtrans<<<(384 * 128 + 255) / 256, 256, 0, stream>>>(ew1, ew1t, 384, 128);
    wtrans<<<(256 * 256 + 255) / 256, 256, 0, stream>>>(dw0, dw0t, 256, 256);
    wtrans<<<(256 * 128 + 255) / 256, 256, 0, stream>>>(dw1, dw1t, 256, 128);
    wtrans<<<(128 * 128 + 255) / 256, 256, 0, stream>>>(sw0, sw0t, 128, 128);
    wtrans<<<(128 * 128 + 255) / 256, 256, 0, stream>>>(sw1, sw1t, 128, 128);

    bin_kernel<<<(E + 255) / 256, 256, 0, stream>>>(dst_idx, cursor, elist, E);

    float* e_out  = (float*)d_out;
    float* hs_out = e_out + (size_t)E * 128;
    float* hd_out = hs_out + (size_t)NS * 128;

    edge_kernel<<<(E + 127) / 128, 1024, 0, stream>>>(
        e_h, h_src, h_dst, src_idx, dst_idx,
        ew0t, eb0, eg0, ebt0, ew1t, eb1, eg1, ebt1,
        e_new, e_out, E);

    src_kernel<<<(NS + 63) / 64, 512, 0, stream>>>(
        h_src, sw0t, sb0, sg0, sbt0, sw1t, sb1, sg1, sbt1, hs_out, NS);

    dst_kernel<<<(ND + 63) / 64, 512, 0, stream>>>(
        h_dst, e_new, e_out, e_h, elist, cursor,
        dw0t, db0, dg0, dbt0, dw1t, db1, dg1, dbt1,
        hd_out, ND);
}

// Round 7
// 718.518 us; speedup vs baseline: 1.2526x; 1.2526x over previous
//
#include <hip/hip_runtime.h>

typedef short short8 __attribute__((ext_vector_type(8)));
typedef float f32x4 __attribute__((ext_vector_type(4)));
typedef unsigned short u16;
typedef unsigned int u32;

__device__ __forceinline__ u32 cvt2(float a, float b) {
    u32 r; asm("v_cvt_pk_bf16_f32 %0, %1, %2" : "=v"(r) : "v"(a), "v"(b)); return r;
}
__device__ __forceinline__ u16 f2bf(float f) {
    u32 r; asm("v_cvt_pk_bf16_f32 %0, %1, %1" : "=v"(r) : "v"(f)); return (u16)r;
}
__device__ __forceinline__ float bf2f(u16 b) {
    union { u32 u; float f; } v; v.u = ((u32)b) << 16; return v.f;
}

// One MLP layer: X (bf16 LDS [64][K+8]) @ Wt (bf16 global [N][K]) + bias,
// row LayerNorm, opt SiLU.  NWA active waves; wave w owns cols [w*N/NWA,(w+1)*N/NWA).
// B loads are register double/triple-buffered from global (L2-resident weights);
// K-loop is barrier-free.  Cross-wave LN reduce via LDS float atomics (red ping-pong).
// OMODE 0: bf16 to Ol (stride N+8), trailing barrier.
// OMODE 1: fused global epilogue: gout = resid + (degv? mask(h) : h); bout = bf16(h).
template<int K, int N, int NWA, bool SILU, int OMODE>
__device__ __forceinline__ void mlp_layer(
    const u16* Xl, u16* Ol,
    float* red_cur, float* red_next,
    const u16* __restrict__ Wt, const float* __restrict__ bias,
    const float* __restrict__ gamma, const float* __restrict__ beta,
    const float* resid, float* gout, u16* bout, const u32* degv, int rowsv)
{
    constexpr int LDX = K + 8;
    constexpr int LDO = N + 8;
    constexpr int NT = N / (16 * NWA);
    constexpr int KS = K / 32;
    static_assert(N % (16 * NWA) == 0 && NT >= 1 && (KS % 2) == 0, "bad split");
    const int tid = threadIdx.x;
    const int wave = tid >> 6;
    const int lane = tid & 63;
    const int l15 = lane & 15;
    const int lg = lane >> 4;

    f32x4 acc[4][NT];

    if (wave < NWA) {
        const int nbase = wave * (N / NWA);
        const u16* wp[NT];
        #pragma unroll
        for (int nt = 0; nt < NT; ++nt)
            wp[nt] = Wt + (size_t)(nbase + nt * 16 + l15) * K + lg * 8;
        const u16* xp = Xl + l15 * LDX + lg * 8;

        #pragma unroll
        for (int mt = 0; mt < 4; ++mt)
            #pragma unroll
            for (int nt = 0; nt < NT; ++nt)
                acc[mt][nt] = (f32x4){0.f, 0.f, 0.f, 0.f};

        short8 a[4];

#define BLOAD(ks, arr) { _Pragma("unroll") \
    for (int nt = 0; nt < NT; ++nt) arr[nt] = *(const short8*)(wp[nt] + (ks) * 32); }
#define ALOAD(ks) { _Pragma("unroll") \
    for (int mt = 0; mt < 4; ++mt) a[mt] = *(const short8*)(xp + mt * 16 * LDX + (ks) * 32); }
#define MFMAS(arr) { _Pragma("unroll") \
    for (int nt = 0; nt < NT; ++nt) { _Pragma("unroll") \
        for (int mt = 0; mt < 4; ++mt) \
            acc[mt][nt] = __builtin_amdgcn_mfma_f32_16x16x32_bf16(a[mt], arr[nt], acc[mt][nt], 0, 0, 0); } }

        if (NT == 1) {
            // 3-deep register ring (K-loop is the latency-exposed part at NT=1)
            short8 b0[NT], b1[NT], b2[NT];
            BLOAD(0, b0);
            BLOAD(1, b1);
            #pragma unroll
            for (int ks = 0; ks < KS; ++ks) {
                if (ks + 2 < KS) {
                    if (ks % 3 == 0) { BLOAD(ks + 2, b2); }
                    else if (ks % 3 == 1) { BLOAD(ks + 2, b0); }
                    else { BLOAD(ks + 2, b1); }
                }
                ALOAD(ks);
                if (ks % 3 == 0) { MFMAS(b0); }
                else if (ks % 3 == 1) { MFMAS(b1); }
                else { MFMAS(b2); }
            }
        } else {
            short8 b0[NT], b1[NT];
            BLOAD(0, b0);
            #pragma unroll
            for (int ks = 0; ks < KS; ++ks) {
                if (ks + 1 < KS) {
                    if (ks & 1) { BLOAD(ks + 1, b0); } else { BLOAD(ks + 1, b1); }
                }
                ALOAD(ks);
                if (ks & 1) { MFMAS(b1); } else { MFMAS(b0); }
            }
        }
#undef BLOAD
#undef ALOAD
#undef MFMAS

        // bias (loaded post-loop: keeps K-loop register pressure down) + partial (s,q)
        float bv[NT];
        #pragma unroll
        for (int nt = 0; nt < NT; ++nt) bv[nt] = bias[nbase + nt * 16 + l15];
        #pragma unroll
        for (int mt = 0; mt < 4; ++mt) {
            float s[4] = {0.f, 0.f, 0.f, 0.f}, q[4] = {0.f, 0.f, 0.f, 0.f};
            #pragma unroll
            for (int nt = 0; nt < NT; ++nt)
                #pragma unroll
                for (int r = 0; r < 4; ++r) {
                    float v = acc[mt][nt][r] + bv[nt];
                    acc[mt][nt][r] = v;
                    s[r] += v; q[r] += v * v;
                }
            #pragma unroll
            for (int o = 1; o < 16; o <<= 1)
                #pragma unroll
                for (int r = 0; r < 4; ++r) {
                    s[r] += __shfl_xor(s[r], o, 64);
                    q[r] += __shfl_xor(q[r], o, 64);
                }
            if (l15 == 0) {
                int row = mt * 16 + lg * 4;
                #pragma unroll
                for (int r = 0; r < 4; ++r) {
                    atomicAdd(&red_cur[(row + r) * 2 + 0], s[r]);
                    atomicAdd(&red_cur[(row + r) * 2 + 1], q[r]);
                }
            }
        }
    }
    __syncthreads();                        // B1: partials complete; all X reads done
    if (tid < 128) red_next[tid] = 0.f;     // ping-pong buffer for next layer

    if (wave < NWA) {
        const int nbase = wave * (N / NWA);
        float gv[NT], btv[NT];
        #pragma unroll
        for (int nt = 0; nt < NT; ++nt) {
            int n = nbase + nt * 16 + l15;
            gv[nt] = gamma[n]; btv[nt] = beta[n];
        }
        constexpr float invN = 1.f / (float)N;
        #pragma unroll
        for (int mt = 0; mt < 4; ++mt)
            #pragma unroll
            for (int r = 0; r < 4; ++r) {
                int row = mt * 16 + lg * 4 + r;
                float2 sq = *(const float2*)&red_cur[row * 2];
                float mean = sq.x * invN;
                float rstd = rsqrtf(sq.y * invN - mean * mean + 1e-5f);
                #pragma unroll
                for (int nt = 0; nt < NT; ++nt) {
                    float h = (acc[mt][nt][r] - mean) * rstd * gv[nt] + btv[nt];
                    if (SILU) h = h * __builtin_amdgcn_rcpf(1.f + __expf(-h));
                    int col = nbase + nt * 16 + l15;
                    if constexpr (OMODE == 0) {
                        Ol[row * LDO + col] = f2bf(h);
                    } else {
                        if (row < rowsv) {
                            float base = resid[row * 128 + col];
                            float val = h;
                            if (degv) val = (degv[row] > 0u) ? h : 0.f;
                            gout[row * 128 + col] = base + val;
                            if (bout) bout[row * 128 + col] = f2bf(h);
                        }
                    }
                }
            }
    }
    if constexpr (OMODE == 0) __syncthreads();   // B2: Ol visible (Ol may alias Xl)
}

// ---------------- edge binning: elist[dst*64 + slot] = e
__global__ __launch_bounds__(256) void bin_kernel(
    const int* __restrict__ dst_idx, u32* __restrict__ cursor,
    int* __restrict__ elist, int E)
{
    int e = blockIdx.x * 256 + threadIdx.x;
    if (e < E) {
        int d = dst_idx[e];
        u32 slot = atomicAdd(&cursor[d], 1u);
        if (slot < 64u) elist[(size_t)d * 64 + slot] = e;
    }
}

// ---------------- edge kernel: 12 waves, 64 edges/block; MLP(384->384->128), fused epilogue
__global__ __launch_bounds__(768, 6) void edge_kernel(
    const float* __restrict__ e_h, const float* __restrict__ h_src, const float* __restrict__ h_dst,
    const int* __restrict__ src_idx, const int* __restrict__ dst_idx,
    const u16* __restrict__ ew0t, const float* __restrict__ eb0, const float* __restrict__ eg0, const float* __restrict__ ebt0,
    const u16* __restrict__ ew1t, const float* __restrict__ eb1, const float* __restrict__ eg1, const float* __restrict__ ebt1,
    u16* __restrict__ e_new,          // may be null -> dst kernel recomputes from e_out - e_h
    float* __restrict__ e_out, int E)
{
    __shared__ alignas(16) u16 Xbuf[64 * 392];   // 50176 B: X / H1 in place
    __shared__ alignas(8) float red[2][128];
    const int tid = threadIdx.x;
    const int eBase = blockIdx.x * 64;
    const int rowsv = min(64, E - eBase);

    if (tid < 256) ((float*)red)[tid] = 0.f;

    // stage X = [e_h | h_src[s] | h_dst[d]] as bf16; 12 threads/row, 8 float4 each
    {
        const int row = tid / 12;
        const int q12 = tid - row * 12;
        if (row < 64) {
            u16* xr = Xbuf + row * 392;
            if (row < rowsv) {
                int e = eBase + row;
                const float* pe = e_h   + (size_t)e * 128;
                const float* ps = h_src + (size_t)src_idx[e] * 128;
                const float* pd = h_dst + (size_t)dst_idx[e] * 128;
                #pragma unroll
                for (int j = 0; j < 8; ++j) {
                    int col = (q12 + j * 12) * 4;           // 0..380
                    const float* p = (col < 128) ? (pe + col)
                                   : (col < 256) ? (ps + col - 128)
                                                 : (pd + col - 256);
                    float4 v = *(const float4*)p;
                    *(uint2*)(xr + col) = make_uint2(cvt2(v.x, v.y), cvt2(v.z, v.w));
                }
            } else {
                #pragma unroll
                for (int j = 0; j < 8; ++j) {
                    int col = (q12 + j * 12) * 4;
                    *(uint2*)(xr + col) = make_uint2(0u, 0u);
                }
            }
        }
    }
    __syncthreads();

    mlp_layer<384, 384, 12, true, 0>(
        Xbuf, Xbuf, red[0], red[1], ew0t, eb0, eg0, ebt0,
        nullptr, nullptr, nullptr, nullptr, rowsv);

    mlp_layer<384, 128, 8, false, 1>(
        Xbuf, nullptr, red[1], red[0], ew1t, eb1, eg1, ebt1,
        e_h + (size_t)eBase * 128, e_out + (size_t)eBase * 128,
        e_new ? e_new + (size_t)eBase * 128 : (u16*)nullptr, nullptr, rowsv);
}

// ---------------- dst kernel: [h_dst | gather-sum(e_new)] -> MLP(256->256->128), deg mask, residual
__global__ __launch_bounds__(512, 6) void dst_kernel(
    const float* __restrict__ h_dst,
    const u16* __restrict__ e_new,       // fast path; may be null
    const float* __restrict__ e_out, const float* __restrict__ e_h,   // fallback
    const int* __restrict__ elist, const u32* __restrict__ cursor,
    const u16* __restrict__ dw0t, const float* __restrict__ db0, const float* __restrict__ dg0, const float* __restrict__ dbt0,
    const u16* __restrict__ dw1t, const float* __restrict__ db1, const float* __restrict__ dg1, const float* __restrict__ dbt1,
    float* __restrict__ hd_out, int ND)
{
    __shared__ alignas(16) u16 Xbuf[64 * 264];   // 33792 B
    __shared__ alignas(8) float red[2][128];
    const int tid = threadIdx.x;
    const int nBase = blockIdx.x * 64;
    const int rowsv = min(64, ND - nBase);

    if (tid < 256) ((float*)red)[tid] = 0.f;

    // left half: h_dst -> bf16 (8 threads/row, 4 float4 each)
    {
        const int row = tid >> 3, q8 = tid & 7;
        int n = nBase + row;
        u16* xr = Xbuf + row * 264;
        #pragma unroll
        for (int j = 0; j < 4; ++j) {
            int col = (q8 + j * 8) * 4;
            float4 v = make_float4(0.f, 0.f, 0.f, 0.f);
            if (n < ND) v = *(const float4*)(h_dst + (size_t)n * 128 + col);
            *(uint2*)(xr + col) = make_uint2(cvt2(v.x, v.y), cvt2(v.z, v.w));
        }
    }
    // right half: m_sum via per-dst edge-list gather. 8 threads/row, 16 cols each.
    {
        const int r = tid >> 3, q = tid & 7;
        const int n = nBase + r;
        float accm[16];
        #pragma unroll
        for (int c = 0; c < 16; ++c) accm[c] = 0.f;
        if (n < ND) {
            int dg = min((int)cursor[n], 64);
            const int* el = elist + (size_t)n * 64;
            if (e_new) {
                for (int j = 0; j < dg; ++j) {
                    const u16* p = e_new + (size_t)el[j] * 128 + q * 16;
                    #pragma unroll
                    for (int t = 0; t < 2; ++t) {
                        short8 v = *(const short8*)(p + t * 8);
                        #pragma unroll
                        for (int c = 0; c < 8; ++c) accm[t * 8 + c] += bf2f((u16)v[c]);
                    }
                }
            } else {
                for (int j = 0; j < dg; ++j) {
                    const float* po = e_out + (size_t)el[j] * 128 + q * 16;
                    const float* ph = e_h  + (size_t)el[j] * 128 + q * 16;
                    #pragma unroll
                    for (int t = 0; t < 4; ++t) {
                        float4 vo = *(const float4*)(po + t * 4);
                        float4 vh = *(const float4*)(ph + t * 4);
                        accm[t * 4 + 0] += vo.x - vh.x;
                        accm[t * 4 + 1] += vo.y - vh.y;
                        accm[t * 4 + 2] += vo.z - vh.z;
                        accm[t * 4 + 3] += vo.w - vh.w;
                    }
                }
            }
        }
        #pragma unroll
        for (int c4 = 0; c4 < 4; ++c4)
            *(uint2*)(Xbuf + r * 264 + 128 + q * 16 + c4 * 4) =
                make_uint2(cvt2(accm[c4 * 4 + 0], accm[c4 * 4 + 1]),
                           cvt2(accm[c4 * 4 + 2], accm[c4 * 4 + 3]));
    }
    __syncthreads();

    mlp_layer<256, 256, 8, true, 0>(
        Xbuf, Xbuf, red[0], red[1], dw0t, db0, dg0, dbt0,
        nullptr, nullptr, nullptr, nullptr, rowsv);

    mlp_layer<256, 128, 8, false, 1>(
        Xbuf, nullptr, red[1], red[0], dw1t, db1, dg1, dbt1,
        h_dst + (size_t)nBase * 128, hd_out + (size_t)nBase * 128,
        (u16*)nullptr, cursor + nBase, rowsv);
}

// ---------------- src kernel: h_src -> MLP(128->128->128), residual
__global__ __launch_bounds__(512, 6) void src_kernel(
    const float* __restrict__ h_src,
    const u16* __restrict__ sw0t, const float* __restrict__ sb0, const float* __restrict__ sg0, const float* __restrict__ sbt0,
    const u16* __restrict__ sw1t, const float* __restrict__ sb1, const float* __restrict__ sg1, const float* __restrict__ sbt1,
    float* __restrict__ hs_out, int NS)
{
    __shared__ alignas(16) u16 Xbuf[64 * 136];
    __shared__ alignas(8) float red[2][128];
    const int tid = threadIdx.x;
    const int nBase = blockIdx.x * 64;
    const int rowsv = min(64, NS - nBase);

    if (tid < 256) ((float*)red)[tid] = 0.f;

    {
        const int row = tid >> 3, q8 = tid & 7;
        int n = nBase + row;
        u16* xr = Xbuf + row * 136;
        #pragma unroll
        for (int j = 0; j < 4; ++j) {
            int col = (q8 + j * 8) * 4;
            float4 v = make_float4(0.f, 0.f, 0.f, 0.f);
            if (n < NS) v = *(const float4*)(h_src + (size_t)n * 128 + col);
            *(uint2*)(xr + col) = make_uint2(cvt2(v.x, v.y), cvt2(v.z, v.w));
        }
    }
    __syncthreads();

    mlp_layer<128, 128, 8, true, 0>(
        Xbuf, Xbuf, red[0], red[1], sw0t, sb0, sg0, sbt0,
        nullptr, nullptr, nullptr, nullptr, rowsv);

    mlp_layer<128, 128, 8, false, 1>(
        Xbuf, nullptr, red[1], red[0], sw1t, sb1, sg1, sbt1,
        h_src + (size_t)nBase * 128, hs_out + (size_t)nBase * 128,
        (u16*)nullptr, nullptr, rowsv);
}

// ---------------- weight transpose+cast: W[k][n] f32 -> Wt[n][k] bf16
__global__ __launch_bounds__(256) void wtrans(const float* __restrict__ W, u16* __restrict__ Wt, int K, int N) {
    int i = blockIdx.x * 256 + threadIdx.x;
    if (i < K * N) {
        int k = i / N, n = i % N;
        Wt[(size_t)n * K + k] = f2bf(W[i]);
    }
}

extern "C" void kernel_launch(void* const* d_in, const int* in_sizes, int n_in,
                              void* d_out, int out_size, void* d_ws, size_t ws_size,
                              hipStream_t stream) {
    const float* e_h   = (const float*)d_in[0];
    const float* h_src = (const float*)d_in[1];
    const float* h_dst = (const float*)d_in[2];
    const int* src_idx = (const int*)d_in[3];
    const int* dst_idx = (const int*)d_in[4];
    const float* ew0 = (const float*)d_in[5];
    const float* eb0 = (const float*)d_in[6];
    const float* eg0 = (const float*)d_in[7];
    const float* ebt0 = (const float*)d_in[8];
    const float* ew1 = (const float*)d_in[9];
    const float* eb1 = (const float*)d_in[10];
    const float* eg1 = (const float*)d_in[11];
    const float* ebt1 = (const float*)d_in[12];
    const float* dw0 = (const float*)d_in[13];
    const float* db0 = (const float*)d_in[14];
    const float* dg0 = (const float*)d_in[15];
    const float* dbt0 = (const float*)d_in[16];
    const float* dw1 = (const float*)d_in[17];
    const float* db1 = (const float*)d_in[18];
    const float* dg1 = (const float*)d_in[19];
    const float* dbt1 = (const float*)d_in[20];
    const float* sw0 = (const float*)d_in[21];
    const float* sb0 = (const float*)d_in[22];
    const float* sg0 = (const float*)d_in[23];
    const float* sbt0 = (const float*)d_in[24];
    const float* sw1 = (const float*)d_in[25];
    const float* sb1 = (const float*)d_in[26];
    const float* sg1 = (const float*)d_in[27];
    const float* sbt1 = (const float*)d_in[28];

    const int E  = in_sizes[0] / 128;
    const int NS = in_sizes[1] / 128;
    const int ND = in_sizes[2] / 128;

    // workspace carve-up (16B-aligned chunks)
    char* ws = (char*)d_ws;
    size_t off = 0;
    int* elist = (int*)(ws + off);  off += (size_t)ND * 64 * 4;
    u32* cursor = (u32*)(ws + off); off += (size_t)ND * 4;
    u16* ew0t = (u16*)(ws + off);   off += (size_t)384 * 384 * 2;
    u16* ew1t = (u16*)(ws + off);   off += (size_t)128 * 384 * 2;
    u16* dw0t = (u16*)(ws + off);   off += (size_t)256 * 256 * 2;
    u16* dw1t = (u16*)(ws + off);   off += (size_t)128 * 256 * 2;
    u16* sw0t = (u16*)(ws + off);   off += (size_t)128 * 128 * 2;
    u16* sw1t = (u16*)(ws + off);   off += (size_t)128 * 128 * 2;
    off = (off + 255) & ~(size_t)255;
    u16* e_new = (u16*)(ws + off);
    size_t need = off + (size_t)E * 128 * 2;
    if (ws_size < need) e_new = nullptr;   // fallback: dst kernel recomputes from e_out - e_h

    hipMemsetAsync(cursor, 0, (size_t)ND * 4, stream);

    wtrans<<<(384 * 384 + 255) / 256, 256, 0, stream>>>(ew0, ew0t, 384, 384);
    wtrans<<<(384 * 128 + 255) / 256, 256, 0, stream>>>(ew1, ew1t, 384, 128);
    wtrans<<<(256 * 256 + 255) / 256, 256, 0, stream>>>(dw0, dw0t, 256, 256);
    wtrans<<<(256 * 128 + 255) / 256, 256, 0, stream>>>(dw1, dw1t, 256, 128);
    wtrans<<<(128 * 128 + 255) / 256, 256, 0, stream>>>(sw0, sw0t, 128, 128);
    wtrans<<<(128 * 128 + 255) / 256, 256, 0, stream>>>(sw1, sw1t, 128, 128);

    bin_kernel<<<(E + 255) / 256, 256, 0, stream>>>(dst_idx, cursor, elist, E);

    float* e_out  = (float*)d_out;
    float* hs_out = e_out + (size_t)E * 128;
    float* hd_out = hs_out + (size_t)NS * 128;

    edge_kernel<<<(E + 63) / 64, 768, 0, stream>>>(
        e_h, h_src, h_dst, src_idx, dst_idx,
        ew0t, eb0, eg0, ebt0, ew1t, eb1, eg1, ebt1,
        e_new, e_out, E);

    src_kernel<<<(NS + 63) / 64, 512, 0, stream>>>(
        h_src, sw0t, sb0, sg0, sbt0, sw1t, sb1, sg1, sbt1, hs_out, NS);

    dst_kernel<<<(ND + 63) / 64, 512, 0, stream>>>(
        h_dst, e_new, e_out, e_h, elist, cursor,
        dw0t, db0, dg0, dbt0, dw1t, db1, dg1, dbt1,
        hd_out, ND);
}